// Round 3
// baseline (105.656 us; speedup 1.0000x reference)
//
#include <hip/hip_runtime.h>
#include <hip/hip_cooperative_groups.h>
#include <math.h>

// AcidSynth: time-varying biquad as a hierarchical parallel affine scan,
// fully fused into ONE cooperative kernel.
// s[t] = A_t s[t-1] + d_t,  A_t = [[-a1,1],[-a2,0]] (companion structure).
// Phase A: per-thread 16-sample chunk transform (coefs kept in registers),
//          block-level scan -> per-block total Bt (4 KB in d_ws).
// grid.sync()
// Phase B: every block redundantly scans the 128 block totals (L2-hot),
//          combines with the register-resident per-chunk exclusive prefix,
//          replays 16 samples + tanh from registers. No Pf roundtrip.

namespace cg = cooperative_groups;

#define LCHUNK 16
#define NBLK 128

struct Aff { float m00,m01,m10,m11,c0,c1; };

__device__ __forceinline__ Aff aff_identity(){ return Aff{1.f,0.f,0.f,1.f,0.f,0.f}; }

// returns B∘A (A applied first)
__device__ __forceinline__ Aff aff_compose(const Aff& B, const Aff& A){
  Aff r;
  r.m00 = fmaf(B.m00, A.m00, B.m01*A.m10);
  r.m01 = fmaf(B.m00, A.m01, B.m01*A.m11);
  r.m10 = fmaf(B.m10, A.m00, B.m11*A.m10);
  r.m11 = fmaf(B.m10, A.m01, B.m11*A.m11);
  r.c0  = fmaf(B.m00, A.c0, fmaf(B.m01, A.c1, B.c0));
  r.c1  = fmaf(B.m10, A.c0, fmaf(B.m11, A.c1, B.c1));
  return r;
}

__device__ __forceinline__ Aff aff_shfl_up(const Aff& a, int delta){
  Aff r;
  r.m00 = __shfl_up(a.m00, delta, 64);
  r.m01 = __shfl_up(a.m01, delta, 64);
  r.m10 = __shfl_up(a.m10, delta, 64);
  r.m11 = __shfl_up(a.m11, delta, 64);
  r.c0  = __shfl_up(a.c0 , delta, 64);
  r.c1  = __shfl_up(a.c1 , delta, 64);
  return r;
}

// RBJ lowpass coefficients; na1 = -a1, na2 = -a2 (normalized), b2 == b0, b1 == 2*b0.
__device__ __forceinline__ void coefs(float wv, float qv,
                                      float& na1, float& na2, float& b0){
  float rev = fmaf(wv, 7900.0f/48000.0f, 100.0f/48000.0f);
  float cw = __builtin_amdgcn_cosf(rev);
  float sw = __builtin_amdgcn_sinf(rev);
  float qq = fmaf(qv, 8.0f - 0.7071f, 0.7071f);
  float af = sw * (0.5f * __builtin_amdgcn_rcpf(qq));
  float ia = __builtin_amdgcn_rcpf(1.0f + af);
  float t1 = 1.0f - cw;
  b0 = 0.5f * (t1 * ia);
  na1 = (cw + cw) * ia;
  na2 = (af - 1.0f) * ia;
}

__device__ __forceinline__ void get_controls(const float* midi01, const float* alpha01,
                                             const float* phasep,
                                             float& alpha, float& f0c, float& phase0){
  #pragma clang fp contract(off)
  alpha = alpha01[0]*2.8f + 0.2f;
  float md = rintf(midi01[0]*30.0f + 30.0f);          // np.round: half-even
  float f0 = 440.0f * exp2f((md - 69.0f)/12.0f);
  f0c = 6.2831855f * f0;                              // 2*pi*f0 in f32, ref op order
  phase0 = phasep[0];
}

// dry[i] = 0.5*sq*env; replicate reference f32 op order (no contraction) to keep
// the square-wave sign decision bit-faithful.
__device__ __forceinline__ float osc_dry(int i, float alpha, float f0c, float phase0){
  #pragma clang fp contract(off)
  float tf = (float)i;
  float u = 1.0f - tf/6000.0f;                        // NOTE_ON_DUR*SR = 6000
  u = fminf(fmaxf(u, 0.0f), 1.0f);
  float env = powf(u, alpha);
  float arg = phase0 + (f0c*tf)/48000.0f;
  float d = arg/6.2831855f;
  float m = d - floorf(d);
  float sq = (m < 0.5f) ? 1.0f : -1.0f;
  return (0.5f*sq)*env;
}

__global__ __launch_bounds__(256) void k_fused(const float* __restrict__ w,
    const float* __restrict__ qm, const float* __restrict__ midi01,
    const float* __restrict__ alpha01, const float* __restrict__ phasep,
    const float* __restrict__ zi, float4* __restrict__ Bt,
    float* __restrict__ out){
  cg::grid_group grid = cg::this_grid();
  const int tid = threadIdx.x;
  const int blk = blockIdx.x;
  const int lane = tid & 63, wv = tid >> 6;
  const int g = blk*256 + tid;
  const int base = g * LCHUNK;

  // ---------- phase A: chunk transform, coefs cached in registers ----------
  float na1s[LCHUNK], na2s[LCHUNK], b0s[LCHUNK], xs[LCHUNK];
  const bool has_dry = (base < 6000);
  float alpha=0.f, f0c=0.f, phase0=0.f;
  if (has_dry) get_controls(midi01, alpha01, phasep, alpha, f0c, phase0);
  {
    const float4* w4p = reinterpret_cast<const float4*>(w + base);
    const float4* q4p = reinterpret_cast<const float4*>(qm + base);
    #pragma unroll
    for (int j=0;j<LCHUNK/4;j++){
      float4 w4 = w4p[j];
      float4 q4 = q4p[j];
      #pragma unroll
      for (int e=0;e<4;e++){
        int i = j*4 + e;
        coefs((&w4.x)[e], (&q4.x)[e], na1s[i], na2s[i], b0s[i]);
        xs[i] = has_dry ? osc_dry(base + i, alpha, f0c, phase0) : 0.0f;
      }
    }
  }
  float m00=1.f, m01=0.f, m10=0.f, m11=1.f, c0=0.f, c1=0.f;
  #pragma unroll
  for (int i=0;i<LCHUNK;i++){
    float na1 = na1s[i], na2 = na2s[i], b0 = b0s[i];
    float nm00 = fmaf(na1, m00, m10);
    float nm01 = fmaf(na1, m01, m11);
    m10 = na2*m00; m11 = na2*m01;
    m00 = nm00;   m01 = nm01;
    float nc0 = fmaf(na1, c0, c1);
    float nc1 = na2*c0;
    if (has_dry){
      float b1 = b0 + b0;
      float x = xs[i];
      nc0 = fmaf(fmaf(na1,b0,b1), x, nc0);   // d0 = (b1 - a1*b0)*x
      nc1 = fmaf(fmaf(na2,b0,b0), x, nc1);   // d1 = (b2 - a2*b0)*x, b2==b0
    }
    c0 = nc0; c1 = nc1;
  }

  // ---------- block-level scan over the 256 chunk transforms ----------
  Aff Tin{m00,m01,m10,m11,c0,c1};
  #pragma unroll
  for (int off=1; off<64; off<<=1){
    Aff P = aff_shfl_up(Tin, off);
    if (lane >= off) Tin = aff_compose(Tin, P);
  }
  __shared__ float wt[4][6];
  if (lane == 63){
    wt[wv][0]=Tin.m00; wt[wv][1]=Tin.m01; wt[wv][2]=Tin.m10;
    wt[wv][3]=Tin.m11; wt[wv][4]=Tin.c0;  wt[wv][5]=Tin.c1;
  }
  __syncthreads();
  Aff Wp = aff_identity();
  for (int j=0;j<wv;j++){
    Aff Wj{wt[j][0],wt[j][1],wt[j][2],wt[j][3],wt[j][4],wt[j][5]};
    Wp = aff_compose(Wj, Wp);
  }
  Aff Ex = aff_shfl_up(Tin, 1);
  if (lane == 0) Ex = aff_identity();
  Aff Epre = aff_compose(Ex, Wp);      // exclusive prefix within block (stays in regs)
  if (tid == 255){
    Aff Full = aff_compose(Tin, Wp);   // block total
    Bt[blk*2+0] = make_float4(Full.m00, Full.m01, Full.m10, Full.m11);
    Bt[blk*2+1] = make_float4(Full.c0, Full.c1, 0.f, 0.f);
  }

  grid.sync();

  // ---------- phase B: redundant tiny scan of 128 block totals ----------
  __shared__ float2 stsh[NBLK];
  __shared__ float wtot[6];
  const float z0 = zi[0], z1 = zi[1];
  if (tid < NBLK){
    float4 A4 = Bt[tid*2+0];
    float4 C4 = Bt[tid*2+1];
    Aff T{A4.x,A4.y,A4.z,A4.w,C4.x,C4.y};
    #pragma unroll
    for (int off=1; off<64; off<<=1){
      Aff P = aff_shfl_up(T, off);
      if (lane >= off) T = aff_compose(T, P);
    }
    if (tid == 63){
      wtot[0]=T.m00; wtot[1]=T.m01; wtot[2]=T.m10;
      wtot[3]=T.m11; wtot[4]=T.c0;  wtot[5]=T.c1;
    }
    __syncthreads();
    if (tid >= 64){
      Aff W0{wtot[0],wtot[1],wtot[2],wtot[3],wtot[4],wtot[5]};
      T = aff_compose(T, W0);
    }
    float s0 = fmaf(T.m00, z0, fmaf(T.m01, z1, T.c0));
    float s1 = fmaf(T.m10, z0, fmaf(T.m11, z1, T.c1));
    stsh[tid] = make_float2(s0, s1);
  } else {
    __syncthreads();
  }
  __syncthreads();
  const float2 e = (blk == 0) ? make_float2(z0, z1) : stsh[blk-1];

  // ---------- replay own chunk from register-resident coefs ----------
  float u1 = fmaf(Epre.m00, e.x, fmaf(Epre.m01, e.y, Epre.c0));
  float u2 = fmaf(Epre.m10, e.x, fmaf(Epre.m11, e.y, Epre.c1));
  float4* o4p = reinterpret_cast<float4*>(out + base);
  #pragma unroll
  for (int j=0;j<LCHUNK/4;j++){
    float4 ov;
    #pragma unroll
    for (int ecnt=0;ecnt<4;ecnt++){
      int i = j*4 + ecnt;
      float na1 = na1s[i], na2 = na2s[i], b0 = b0s[i];
      float b1 = b0 + b0;
      float x = xs[i];
      float y = fmaf(b0, x, u1);                      // y = b0*x + s1
      float nu1 = fmaf(b1, x, fmaf(na1, y, u2));      // s1' = b1*x - a1*y + s2
      float nu2 = fmaf(b0, x, na2*y);                 // s2' = b2*x - a2*y, b2==b0
      u1 = nu1; u2 = nu2;
      // tanh(y) = 1 - 2/(exp(2y)+1)
      float ey = __expf(y + y);
      float r = __builtin_amdgcn_rcpf(ey + 1.0f);
      (&ov.x)[ecnt] = fmaf(-2.0f, r, 1.0f);
    }
    o4p[j] = ov;
  }
}

// ---------------- fallback: fully sequential (only if shapes/ws mismatch) ----------------
__global__ void k_naive(const float* __restrict__ w, const float* __restrict__ qm,
    const float* __restrict__ midi01, const float* __restrict__ alpha01,
    const float* __restrict__ phasep, const float* __restrict__ zi,
    float* __restrict__ out, int n){
  if (blockIdx.x != 0 || threadIdx.x != 0) return;
  float alpha,f0c,phase0; get_controls(midi01, alpha01, phasep, alpha, f0c, phase0);
  float u1 = zi[0], u2 = zi[1];
  for (int i=0;i<n;i++){
    float na1,na2,b0;
    coefs(w[i], qm[i], na1,na2,b0);
    float b1 = b0 + b0;
    float x = (i < 6000) ? osc_dry(i, alpha, f0c, phase0) : 0.0f;
    float y = fmaf(b0, x, u1);
    float nu1 = fmaf(b1, x, fmaf(na1, y, u2));
    float nu2 = fmaf(b0, x, na2*y);
    u1 = nu1; u2 = nu2;
    float ey = __expf(y + y);
    float r = __builtin_amdgcn_rcpf(ey + 1.0f);
    out[i] = fmaf(-2.0f, r, 1.0f);
  }
}

extern "C" void kernel_launch(void* const* d_in, const int* in_sizes, int n_in,
                              void* d_out, int out_size, void* d_ws, size_t ws_size,
                              hipStream_t stream) {
  const float* midi01  = (const float*)d_in[1];
  const float* alpha01 = (const float*)d_in[2];
  const float* w       = (const float*)d_in[3];
  const float* qm      = (const float*)d_in[4];
  const float* ph      = (const float*)d_in[5];
  const float* zi      = (const float*)d_in[6];
  float* out = (float*)d_out;
  const int n = in_sizes[0];                    // 524288
  const int G = n / LCHUNK;                     // 32768 chunks
  const int B = G / 256;                        // 128 blocks
  const size_t bt_bytes = (size_t)NBLK * 2 * sizeof(float4);

  if ((n % (LCHUNK*256)) != 0 || B != NBLK || ws_size < bt_bytes) {
    k_naive<<<1, 64, 0, stream>>>(w, qm, midi01, alpha01, ph, zi, out, n);
    return;
  }
  float4* Bt = (float4*)d_ws;
  void* args[] = { (void*)&w, (void*)&qm, (void*)&midi01, (void*)&alpha01,
                   (void*)&ph, (void*)&zi, (void*)&Bt, (void*)&out };
  hipError_t err = hipLaunchCooperativeKernel((const void*)k_fused,
                       dim3(NBLK), dim3(256), args, 0, stream);
  if (err != hipSuccess) {
    // cooperative launch unavailable: sequential fallback keeps correctness
    k_naive<<<1, 64, 0, stream>>>(w, qm, midi01, alpha01, ph, zi, out, n);
  }
}

// Round 4
// 85.096 us; speedup vs baseline: 1.2416x; 1.2416x over previous
//
#include <hip/hip_runtime.h>
#include <math.h>

// AcidSynth: time-varying biquad as a hierarchical parallel affine scan,
// fused into ONE plain kernel (no cooperative launch — R3 showed coop launch
// costs +18us inside a captured graph).
// s[t] = A_t s[t-1] + d_t,  A_t = [[-a1,1],[-a2,0]] (companion structure).
// Phase A: per-thread 16-sample chunk transform (coefs kept in registers),
//          block-level scan -> block total published to d_ws + magic flag.
// Flag barrier: spin until all 128 flags are MAGIC (d_ws poison is 0xAA.. so
//          flags need no init; 128 blocks on 256 CUs are always co-resident).
// Phase B: every block redundantly scans the 128 block totals (L2-hot),
//          combines with register-resident per-chunk exclusive prefix,
//          replays 16 samples + tanh. No Pf roundtrip, no recompute.

#define LCHUNK 16
#define NBLK 128
#define FLAG_MAGIC 0x5A17F1A6u

struct Aff { float m00,m01,m10,m11,c0,c1; };

__device__ __forceinline__ Aff aff_identity(){ return Aff{1.f,0.f,0.f,1.f,0.f,0.f}; }

// returns B∘A (A applied first)
__device__ __forceinline__ Aff aff_compose(const Aff& B, const Aff& A){
  Aff r;
  r.m00 = fmaf(B.m00, A.m00, B.m01*A.m10);
  r.m01 = fmaf(B.m00, A.m01, B.m01*A.m11);
  r.m10 = fmaf(B.m10, A.m00, B.m11*A.m10);
  r.m11 = fmaf(B.m10, A.m01, B.m11*A.m11);
  r.c0  = fmaf(B.m00, A.c0, fmaf(B.m01, A.c1, B.c0));
  r.c1  = fmaf(B.m10, A.c0, fmaf(B.m11, A.c1, B.c1));
  return r;
}

__device__ __forceinline__ Aff aff_shfl_up(const Aff& a, int delta){
  Aff r;
  r.m00 = __shfl_up(a.m00, delta, 64);
  r.m01 = __shfl_up(a.m01, delta, 64);
  r.m10 = __shfl_up(a.m10, delta, 64);
  r.m11 = __shfl_up(a.m11, delta, 64);
  r.c0  = __shfl_up(a.c0 , delta, 64);
  r.c1  = __shfl_up(a.c1 , delta, 64);
  return r;
}

// RBJ lowpass coefficients; na1 = -a1, na2 = -a2 (normalized), b2 == b0, b1 == 2*b0.
__device__ __forceinline__ void coefs(float wv, float qv,
                                      float& na1, float& na2, float& b0){
  float rev = fmaf(wv, 7900.0f/48000.0f, 100.0f/48000.0f);
  float cw = __builtin_amdgcn_cosf(rev);
  float sw = __builtin_amdgcn_sinf(rev);
  float qq = fmaf(qv, 8.0f - 0.7071f, 0.7071f);
  float af = sw * (0.5f * __builtin_amdgcn_rcpf(qq));
  float ia = __builtin_amdgcn_rcpf(1.0f + af);
  float t1 = 1.0f - cw;
  b0 = 0.5f * (t1 * ia);
  na1 = (cw + cw) * ia;
  na2 = (af - 1.0f) * ia;
}

__device__ __forceinline__ void get_controls(const float* midi01, const float* alpha01,
                                             const float* phasep,
                                             float& alpha, float& f0c, float& phase0){
  #pragma clang fp contract(off)
  alpha = alpha01[0]*2.8f + 0.2f;
  float md = rintf(midi01[0]*30.0f + 30.0f);          // np.round: half-even
  float f0 = 440.0f * exp2f((md - 69.0f)/12.0f);
  f0c = 6.2831855f * f0;                              // 2*pi*f0 in f32, ref op order
  phase0 = phasep[0];
}

// dry[i] = 0.5*sq*env; replicate reference f32 op order (no contraction) to keep
// the square-wave sign decision bit-faithful.
__device__ __forceinline__ float osc_dry(int i, float alpha, float f0c, float phase0){
  #pragma clang fp contract(off)
  float tf = (float)i;
  float u = 1.0f - tf/6000.0f;                        // NOTE_ON_DUR*SR = 6000
  u = fminf(fmaxf(u, 0.0f), 1.0f);
  float env = powf(u, alpha);
  float arg = phase0 + (f0c*tf)/48000.0f;
  float d = arg/6.2831855f;
  float m = d - floorf(d);
  float sq = (m < 0.5f) ? 1.0f : -1.0f;
  return (0.5f*sq)*env;
}

__global__ __launch_bounds__(256) void k_fused(const float* __restrict__ w,
    const float* __restrict__ qm, const float* __restrict__ midi01,
    const float* __restrict__ alpha01, const float* __restrict__ phasep,
    const float* __restrict__ zi, float4* __restrict__ Bt,
    unsigned int* __restrict__ Flag, float* __restrict__ out){
  const int tid = threadIdx.x;
  const int blk = blockIdx.x;
  const int lane = tid & 63, wv = tid >> 6;
  const int g = blk*256 + tid;
  const int base = g * LCHUNK;

  // ---------- phase A: chunk transform, coefs cached in registers ----------
  float na1s[LCHUNK], na2s[LCHUNK], b0s[LCHUNK], xs[LCHUNK];
  const bool has_dry = (base < 6000);
  float alpha=0.f, f0c=0.f, phase0=0.f;
  if (has_dry) get_controls(midi01, alpha01, phasep, alpha, f0c, phase0);
  {
    const float4* w4p = reinterpret_cast<const float4*>(w + base);
    const float4* q4p = reinterpret_cast<const float4*>(qm + base);
    #pragma unroll
    for (int j=0;j<LCHUNK/4;j++){
      float4 w4 = w4p[j];
      float4 q4 = q4p[j];
      #pragma unroll
      for (int e=0;e<4;e++){
        int i = j*4 + e;
        coefs((&w4.x)[e], (&q4.x)[e], na1s[i], na2s[i], b0s[i]);
        xs[i] = has_dry ? osc_dry(base + i, alpha, f0c, phase0) : 0.0f;
      }
    }
  }
  float m00=1.f, m01=0.f, m10=0.f, m11=1.f, c0=0.f, c1=0.f;
  #pragma unroll
  for (int i=0;i<LCHUNK;i++){
    float na1 = na1s[i], na2 = na2s[i], b0 = b0s[i];
    float nm00 = fmaf(na1, m00, m10);
    float nm01 = fmaf(na1, m01, m11);
    m10 = na2*m00; m11 = na2*m01;
    m00 = nm00;   m01 = nm01;
    float nc0 = fmaf(na1, c0, c1);
    float nc1 = na2*c0;
    if (has_dry){
      float b1 = b0 + b0;
      float x = xs[i];
      nc0 = fmaf(fmaf(na1,b0,b1), x, nc0);   // d0 = (b1 - a1*b0)*x
      nc1 = fmaf(fmaf(na2,b0,b0), x, nc1);   // d1 = (b2 - a2*b0)*x, b2==b0
    }
    c0 = nc0; c1 = nc1;
  }

  // ---------- block-level scan over the 256 chunk transforms ----------
  Aff Tin{m00,m01,m10,m11,c0,c1};
  #pragma unroll
  for (int off=1; off<64; off<<=1){
    Aff P = aff_shfl_up(Tin, off);
    if (lane >= off) Tin = aff_compose(Tin, P);
  }
  __shared__ float wt[4][6];
  if (lane == 63){
    wt[wv][0]=Tin.m00; wt[wv][1]=Tin.m01; wt[wv][2]=Tin.m10;
    wt[wv][3]=Tin.m11; wt[wv][4]=Tin.c0;  wt[wv][5]=Tin.c1;
  }
  __syncthreads();
  Aff Wp = aff_identity();
  for (int j=0;j<wv;j++){
    Aff Wj{wt[j][0],wt[j][1],wt[j][2],wt[j][3],wt[j][4],wt[j][5]};
    Wp = aff_compose(Wj, Wp);
  }
  Aff Ex = aff_shfl_up(Tin, 1);
  if (lane == 0) Ex = aff_identity();
  Aff Epre = aff_compose(Ex, Wp);      // exclusive prefix within block (stays in regs)
  if (tid == 255){
    Aff Full = aff_compose(Tin, Wp);   // block total
    Bt[blk*2+0] = make_float4(Full.m00, Full.m01, Full.m10, Full.m11);
    Bt[blk*2+1] = make_float4(Full.c0, Full.c1, 0.f, 0.f);
    __threadfence();                   // make totals visible device-wide
    __hip_atomic_store(&Flag[blk], FLAG_MAGIC, __ATOMIC_RELEASE,
                       __HIP_MEMORY_SCOPE_AGENT);
  }

  // ---------- flag barrier + redundant tiny scan of 128 block totals ----------
  __shared__ float2 stsh[NBLK];
  __shared__ float wtot[6];
  const float z0 = zi[0], z1 = zi[1];
  if (tid < NBLK){
    // spin until block tid has published (poison 0xAAAAAAAA != MAGIC)
    while (__hip_atomic_load(&Flag[tid], __ATOMIC_ACQUIRE,
                             __HIP_MEMORY_SCOPE_AGENT) != FLAG_MAGIC) {
      __builtin_amdgcn_s_sleep(1);
    }
    float4 A4 = Bt[tid*2+0];
    float4 C4 = Bt[tid*2+1];
    Aff T{A4.x,A4.y,A4.z,A4.w,C4.x,C4.y};
    #pragma unroll
    for (int off=1; off<64; off<<=1){
      Aff P = aff_shfl_up(T, off);
      if (lane >= off) T = aff_compose(T, P);
    }
    if (tid == 63){
      wtot[0]=T.m00; wtot[1]=T.m01; wtot[2]=T.m10;
      wtot[3]=T.m11; wtot[4]=T.c0;  wtot[5]=T.c1;
    }
    __syncthreads();
    if (tid >= 64){
      Aff W0{wtot[0],wtot[1],wtot[2],wtot[3],wtot[4],wtot[5]};
      T = aff_compose(T, W0);
    }
    float s0 = fmaf(T.m00, z0, fmaf(T.m01, z1, T.c0));
    float s1 = fmaf(T.m10, z0, fmaf(T.m11, z1, T.c1));
    stsh[tid] = make_float2(s0, s1);
  } else {
    __syncthreads();
  }
  __syncthreads();
  const float2 e = (blk == 0) ? make_float2(z0, z1) : stsh[blk-1];

  // ---------- replay own chunk from register-resident coefs ----------
  float u1 = fmaf(Epre.m00, e.x, fmaf(Epre.m01, e.y, Epre.c0));
  float u2 = fmaf(Epre.m10, e.x, fmaf(Epre.m11, e.y, Epre.c1));
  float4* o4p = reinterpret_cast<float4*>(out + base);
  #pragma unroll
  for (int j=0;j<LCHUNK/4;j++){
    float4 ov;
    #pragma unroll
    for (int ecnt=0;ecnt<4;ecnt++){
      int i = j*4 + ecnt;
      float na1 = na1s[i], na2 = na2s[i], b0 = b0s[i];
      float b1 = b0 + b0;
      float x = xs[i];
      float y = fmaf(b0, x, u1);                      // y = b0*x + s1
      float nu1 = fmaf(b1, x, fmaf(na1, y, u2));      // s1' = b1*x - a1*y + s2
      float nu2 = fmaf(b0, x, na2*y);                 // s2' = b2*x - a2*y, b2==b0
      u1 = nu1; u2 = nu2;
      // tanh(y) = 1 - 2/(exp(2y)+1)
      float ey = __expf(y + y);
      float r = __builtin_amdgcn_rcpf(ey + 1.0f);
      (&ov.x)[ecnt] = fmaf(-2.0f, r, 1.0f);
    }
    o4p[j] = ov;
  }
}

// ---------------- fallback: fully sequential (only if shapes/ws mismatch) ----------------
__global__ void k_naive(const float* __restrict__ w, const float* __restrict__ qm,
    const float* __restrict__ midi01, const float* __restrict__ alpha01,
    const float* __restrict__ phasep, const float* __restrict__ zi,
    float* __restrict__ out, int n){
  if (blockIdx.x != 0 || threadIdx.x != 0) return;
  float alpha,f0c,phase0; get_controls(midi01, alpha01, phasep, alpha, f0c, phase0);
  float u1 = zi[0], u2 = zi[1];
  for (int i=0;i<n;i++){
    float na1,na2,b0;
    coefs(w[i], qm[i], na1,na2,b0);
    float b1 = b0 + b0;
    float x = (i < 6000) ? osc_dry(i, alpha, f0c, phase0) : 0.0f;
    float y = fmaf(b0, x, u1);
    float nu1 = fmaf(b1, x, fmaf(na1, y, u2));
    float nu2 = fmaf(b0, x, na2*y);
    u1 = nu1; u2 = nu2;
    float ey = __expf(y + y);
    float r = __builtin_amdgcn_rcpf(ey + 1.0f);
    out[i] = fmaf(-2.0f, r, 1.0f);
  }
}

extern "C" void kernel_launch(void* const* d_in, const int* in_sizes, int n_in,
                              void* d_out, int out_size, void* d_ws, size_t ws_size,
                              hipStream_t stream) {
  const float* midi01  = (const float*)d_in[1];
  const float* alpha01 = (const float*)d_in[2];
  const float* w       = (const float*)d_in[3];
  const float* qm      = (const float*)d_in[4];
  const float* ph      = (const float*)d_in[5];
  const float* zi      = (const float*)d_in[6];
  float* out = (float*)d_out;
  const int n = in_sizes[0];                    // 524288
  const int G = n / LCHUNK;                     // 32768 chunks
  const int B = G / 256;                        // 128 blocks
  const size_t bt_bytes   = (size_t)NBLK * 2 * sizeof(float4);
  const size_t flag_bytes = (size_t)NBLK * sizeof(unsigned int);

  if ((n % (LCHUNK*256)) != 0 || B != NBLK || ws_size < bt_bytes + flag_bytes) {
    k_naive<<<1, 64, 0, stream>>>(w, qm, midi01, alpha01, ph, zi, out, n);
    return;
  }
  float4* Bt = (float4*)d_ws;
  unsigned int* Flag = (unsigned int*)((char*)d_ws + bt_bytes);

  k_fused<<<dim3(NBLK), dim3(256), 0, stream>>>(w, qm, midi01, alpha01, ph, zi,
                                                Bt, Flag, out);
}